// Round 1
// baseline (19679.060 us; speedup 1.0000x reference)
//
#include <hip/hip_runtime.h>
#include <math.h>

#define N_RES 2048
#define N_IN  128
#define T_SEQ 2048

// ---------------- Kernel 1: U = input @ W_in^T  -> d_out (row t = U[t]) ----
__global__ __launch_bounds__(256) void u_gemm(
    const float* __restrict__ in, const float* __restrict__ win,
    float* __restrict__ out)
{
  __shared__ float As[64][65];   // pad 65: bank stride 1, broadcast/2-way only
  __shared__ float Bs[64][65];
  const int tid = threadIdx.x;
  const int t0 = blockIdx.y * 64;
  const int n0 = blockIdx.x * 64;
  const int tx = tid & 15, ty = tid >> 4;

  float acc[4][4];
  #pragma unroll
  for (int r = 0; r < 4; ++r)
    #pragma unroll
    for (int c = 0; c < 4; ++c) acc[r][c] = 0.f;

  for (int k0 = 0; k0 < N_IN; k0 += 64) {
    __syncthreads();
    #pragma unroll
    for (int i = 0; i < 4; ++i) {
      int idx = tid + i * 256;          // float4 slot among 1024
      int row = idx >> 4;
      int k4  = (idx & 15) << 2;
      float4 a = *(const float4*)(in  + (size_t)(t0 + row) * N_IN + k0 + k4);
      As[row][k4+0] = a.x; As[row][k4+1] = a.y; As[row][k4+2] = a.z; As[row][k4+3] = a.w;
      float4 b = *(const float4*)(win + (size_t)(n0 + row) * N_IN + k0 + k4);
      Bs[row][k4+0] = b.x; Bs[row][k4+1] = b.y; Bs[row][k4+2] = b.z; Bs[row][k4+3] = b.w;
    }
    __syncthreads();
    for (int k = 0; k < 64; ++k) {
      float a[4], b[4];
      #pragma unroll
      for (int r = 0; r < 4; ++r) a[r] = As[ty*4+r][k];
      #pragma unroll
      for (int c = 0; c < 4; ++c) b[c] = Bs[tx*4+c][k];
      #pragma unroll
      for (int r = 0; r < 4; ++r)
        #pragma unroll
        for (int c = 0; c < 4; ++c) acc[r][c] += a[r] * b[c];
    }
  }
  #pragma unroll
  for (int r = 0; r < 4; ++r) {
    float4 v = make_float4(acc[r][0], acc[r][1], acc[r][2], acc[r][3]);
    *(float4*)(out + (size_t)(t0 + ty*4 + r) * N_RES + n0 + tx*4) = v;
  }
}

// ---------------- two-level grid barrier (monotonic counters) --------------
// ws layout (ints): leaf[g] at ws[g*32] (128B apart), root at ws[512].
__device__ __forceinline__ void grid_barrier(int* ws, int b, int tid, int bi)
{
  __syncthreads();                       // all waves done with this step
  if (tid == 0) {
    __threadfence();                     // release: make x-row stores device-visible
    int* leaf = ws + (b & 7) * 32;
    int* root = ws + 512;
    int old = __hip_atomic_fetch_add(leaf, 1, __ATOMIC_RELAXED, __HIP_MEMORY_SCOPE_AGENT);
    if (old == bi * 32 - 1)              // last arriver in this group of 32
      __hip_atomic_fetch_add(root, 1, __ATOMIC_RELAXED, __HIP_MEMORY_SCOPE_AGENT);
    while (__hip_atomic_load(root, __ATOMIC_RELAXED, __HIP_MEMORY_SCOPE_AGENT) < bi * 8) { }
    __threadfence();                     // acquire: invalidate L1/L2 before x reads
  }
  __syncthreads();
}

// ---------------- Kernel 2: persistent recurrence --------------------------
// 256 blocks x 256 threads. Block b owns output rows [8b,8b+8); thread t owns
// columns [8t,8t+8) -> private 8x8 W_res block in 64 VGPRs (loaded once).
// d_out row t holds U[t] until step t overwrites it with x_t in place.
__global__ __launch_bounds__(256, 1) void esn_recur(
    const float* __restrict__ wres, float* out, int* ws)
{
  const int b = blockIdx.x;
  const int tid = threadIdx.x;
  const int lane = tid & 63;
  const int wave = tid >> 6;
  const int row0 = b * 8;
  const float inv = 0.022097086912079608f;   // 1/sqrt(2048)

  float w[8][8];
  #pragma unroll
  for (int r = 0; r < 8; ++r) {
    const float* p = wres + (size_t)(row0 + r) * N_RES + tid * 8;
    float4 lo = *(const float4*)p;
    float4 hi = *(const float4*)(p + 4);
    w[r][0]=lo.x; w[r][1]=lo.y; w[r][2]=lo.z; w[r][3]=lo.w;
    w[r][4]=hi.x; w[r][5]=hi.y; w[r][6]=hi.z; w[r][7]=hi.w;
  }

  __shared__ float red[8][4];

  // t = 0: x0 = erf(U[0]) * inv  (each block handles its own 8 columns)
  if (tid < 8) {
    float u = out[row0 + tid];
    out[row0 + tid] = erff(u) * inv;
  }

  for (int t = 1; t < T_SEQ; ++t) {
    grid_barrier(ws, b, tid, t);         // separates step t-1 writes from step t reads

    float u = 0.f;
    if (tid < 8) u = out[(size_t)t * N_RES + row0 + tid];   // prefetch own U[t] slots

    const float4* xp = (const float4*)(out + (size_t)(t - 1) * N_RES + tid * 8);
    float4 xa = xp[0];
    float4 xb = xp[1];

    float acc[8];
    #pragma unroll
    for (int r = 0; r < 8; ++r) {
      acc[r] = w[r][0]*xa.x + w[r][1]*xa.y + w[r][2]*xa.z + w[r][3]*xa.w
             + w[r][4]*xb.x + w[r][5]*xb.y + w[r][6]*xb.z + w[r][7]*xb.w;
    }
    // 64-lane butterfly reduction for all 8 rows
    #pragma unroll
    for (int m = 1; m < 64; m <<= 1) {
      #pragma unroll
      for (int r = 0; r < 8; ++r)
        acc[r] += __shfl_xor(acc[r], m, 64);
    }
    if (lane == 0) {
      #pragma unroll
      for (int r = 0; r < 8; ++r) red[r][wave] = acc[r];
    }
    __syncthreads();
    if (tid < 8) {
      float s = red[tid][0] + red[tid][1] + red[tid][2] + red[tid][3];
      out[(size_t)t * N_RES + row0 + tid] = erff(u + s) * inv;
    }
  }
}

extern "C" void kernel_launch(void* const* d_in, const int* in_sizes, int n_in,
                              void* d_out, int out_size, void* d_ws, size_t ws_size,
                              hipStream_t stream)
{
  const float* input = (const float*)d_in[0];
  const float* w_in  = (const float*)d_in[1];
  const float* w_res = (const float*)d_in[2];
  float* out = (float*)d_out;
  int* ws = (int*)d_ws;

  size_t clr = ws_size < 4096 ? ws_size : 4096;
  hipMemsetAsync(d_ws, 0, clr, stream);          // zero barrier counters

  dim3 g1(N_RES / 64, T_SEQ / 64), b1(256);
  hipLaunchKernelGGL(u_gemm, g1, b1, 0, stream, input, w_in, out);

  void* args[] = { (void*)&w_res, (void*)&out, (void*)&ws };
  hipLaunchCooperativeKernel((void*)esn_recur, dim3(256), dim3(256),
                             args, 0, stream);
}

// Round 2
// 9700.038 us; speedup vs baseline: 2.0288x; 2.0288x over previous
//
#include <hip/hip_runtime.h>
#include <math.h>

#define N_RES 2048
#define N_IN  128
#define T_SEQ 2048
#define NB    128      // blocks in recurrence kernel
#define ROWS  16       // output rows per block (NB*ROWS == N_RES)

// ---------------- Kernel 1: U = input @ W_in^T  -> d_out (row t = U[t]) ----
__global__ __launch_bounds__(256) void u_gemm(
    const float* __restrict__ in, const float* __restrict__ win,
    float* __restrict__ out)
{
  __shared__ float As[64][65];
  __shared__ float Bs[64][65];
  const int tid = threadIdx.x;
  const int t0 = blockIdx.y * 64;
  const int n0 = blockIdx.x * 64;
  const int tx = tid & 15, ty = tid >> 4;

  float acc[4][4];
  #pragma unroll
  for (int r = 0; r < 4; ++r)
    #pragma unroll
    for (int c = 0; c < 4; ++c) acc[r][c] = 0.f;

  for (int k0 = 0; k0 < N_IN; k0 += 64) {
    __syncthreads();
    #pragma unroll
    for (int i = 0; i < 4; ++i) {
      int idx = tid + i * 256;
      int row = idx >> 4;
      int k4  = (idx & 15) << 2;
      float4 a = *(const float4*)(in  + (size_t)(t0 + row) * N_IN + k0 + k4);
      As[row][k4+0] = a.x; As[row][k4+1] = a.y; As[row][k4+2] = a.z; As[row][k4+3] = a.w;
      float4 b = *(const float4*)(win + (size_t)(n0 + row) * N_IN + k0 + k4);
      Bs[row][k4+0] = b.x; Bs[row][k4+1] = b.y; Bs[row][k4+2] = b.z; Bs[row][k4+3] = b.w;
    }
    __syncthreads();
    for (int k = 0; k < 64; ++k) {
      float a[4], b[4];
      #pragma unroll
      for (int r = 0; r < 4; ++r) a[r] = As[ty*4+r][k];
      #pragma unroll
      for (int c = 0; c < 4; ++c) b[c] = Bs[tx*4+c][k];
      #pragma unroll
      for (int r = 0; r < 4; ++r)
        #pragma unroll
        for (int c = 0; c < 4; ++c) acc[r][c] += a[r] * b[c];
    }
  }
  #pragma unroll
  for (int r = 0; r < 4; ++r) {
    float4 v = make_float4(acc[r][0], acc[r][1], acc[r][2], acc[r][3]);
    *(float4*)(out + (size_t)(t0 + ty*4 + r) * N_RES + n0 + tx*4) = v;
  }
}

// ---------------- Kernel 2: persistent recurrence --------------------------
// 128 blocks x 256 threads. Block b owns rows [16b,16b+16); thread t owns
// cols [8t,8t+8) -> private 16x8 W block in VGPRs, loaded once.
// All cross-block data (x rows in d_out) moves via agent-scope relaxed
// atomics (LLC-coherent) -> NO fences, NO L2 writeback/invalidate per step.
// Barrier: single monotonic root counter; fire-and-forget add + spin.
__global__ __launch_bounds__(256, 1) void esn_recur(
    const float* __restrict__ wres, float* out, int* ws)
{
  const int b = blockIdx.x;
  const int tid = threadIdx.x;
  const int lane = tid & 63;
  const int wave = tid >> 6;
  const int row0 = b * ROWS;
  const float inv = 0.022097086912079608f;   // 1/sqrt(2048)

  // W block: 16 rows x 8 cols per thread, register-resident
  float w[ROWS][8];
  #pragma unroll
  for (int r = 0; r < ROWS; ++r) {
    const float* p = wres + (size_t)(row0 + r) * N_RES + tid * 8;
    float4 lo = *(const float4*)p;
    float4 hi = *(const float4*)(p + 4);
    w[r][0]=lo.x; w[r][1]=lo.y; w[r][2]=lo.z; w[r][3]=lo.w;
    w[r][4]=hi.x; w[r][5]=hi.y; w[r][6]=hi.z; w[r][7]=hi.w;
  }

  __shared__ float red[ROWS][4];
  int* root = ws;

  // t = 0: x0 = erf(U[0]) * inv  (own columns only; store agent-coherent)
  if (tid < ROWS) {
    float u = out[row0 + tid];
    __hip_atomic_store(out + row0 + tid, erff(u) * inv,
                       __ATOMIC_RELAXED, __HIP_MEMORY_SCOPE_AGENT);
  }

  for (int t = 1; t < T_SEQ; ++t) {
    // ---- arrive: signal step t-1 stores complete (they are wave-0 stores;
    // vmcnt(0) in wave 0 guarantees completion at the LLC).
    asm volatile("s_waitcnt vmcnt(0)" ::: "memory");
    if (tid == 0) {
      __hip_atomic_fetch_add(root, 1, __ATOMIC_RELAXED, __HIP_MEMORY_SCOPE_AGENT);
      while (__hip_atomic_load(root, __ATOMIC_RELAXED, __HIP_MEMORY_SCOPE_AGENT)
             < t * NB) { }
    }
    asm volatile("" ::: "memory");
    __syncthreads();

    // ---- load x_{t-1} (agent-coherent, fresh from LLC) + own U[t] slots
    const float* xrow = out + (size_t)(t - 1) * N_RES + tid * 8;
    float x[8];
    #pragma unroll
    for (int i = 0; i < 8; ++i)
      x[i] = __hip_atomic_load(xrow + i, __ATOMIC_RELAXED, __HIP_MEMORY_SCOPE_AGENT);
    float u = 0.f;
    if (tid < ROWS) u = out[(size_t)t * N_RES + row0 + tid];  // written only by self, later

    // ---- partial matvec: 16 rows x 8 cols
    float acc[ROWS];
    #pragma unroll
    for (int r = 0; r < ROWS; ++r) {
      acc[r] = w[r][0]*x[0] + w[r][1]*x[1] + w[r][2]*x[2] + w[r][3]*x[3]
             + w[r][4]*x[4] + w[r][5]*x[5] + w[r][6]*x[6] + w[r][7]*x[7];
    }
    // ---- 64-lane butterfly for all 16 rows
    #pragma unroll
    for (int m = 1; m < 64; m <<= 1) {
      #pragma unroll
      for (int r = 0; r < ROWS; ++r)
        acc[r] += __shfl_xor(acc[r], m, 64);
    }
    if (lane == 0) {
      #pragma unroll
      for (int r = 0; r < ROWS; ++r) red[r][wave] = acc[r];
    }
    __syncthreads();
    if (tid < ROWS) {
      float s = red[tid][0] + red[tid][1] + red[tid][2] + red[tid][3];
      __hip_atomic_store(out + (size_t)t * N_RES + row0 + tid, erff(u + s) * inv,
                         __ATOMIC_RELAXED, __HIP_MEMORY_SCOPE_AGENT);
    }
  }
}

extern "C" void kernel_launch(void* const* d_in, const int* in_sizes, int n_in,
                              void* d_out, int out_size, void* d_ws, size_t ws_size,
                              hipStream_t stream)
{
  const float* input = (const float*)d_in[0];
  const float* w_in  = (const float*)d_in[1];
  const float* w_res = (const float*)d_in[2];
  float* out = (float*)d_out;
  int* ws = (int*)d_ws;

  size_t clr = ws_size < 4096 ? ws_size : 4096;
  hipMemsetAsync(d_ws, 0, clr, stream);          // zero barrier counter

  dim3 g1(N_RES / 64, T_SEQ / 64), b1(256);
  hipLaunchKernelGGL(u_gemm, g1, b1, 0, stream, input, w_in, out);

  void* args[] = { (void*)&w_res, (void*)&out, (void*)&ws };
  hipLaunchCooperativeKernel((void*)esn_recur, dim3(NB), dim3(256),
                             args, 0, stream);
}

// Round 3
// 8120.729 us; speedup vs baseline: 2.4233x; 1.1945x over previous
//
#include <hip/hip_runtime.h>
#include <math.h>

#define N_RES 2048
#define N_IN  128
#define T_SEQ 2048
#define NB    128      // blocks in recurrence kernel
#define ROWS  16       // output rows per block (NB*ROWS == N_RES)
#define FSTR  4        // ints per flag slot (16 B) -> spread LLC lines/channels

// ---------------- Kernel 1: U = input @ W_in^T  -> d_out (row t = U[t]) ----
__global__ __launch_bounds__(256) void u_gemm(
    const float* __restrict__ in, const float* __restrict__ win,
    float* __restrict__ out)
{
  __shared__ float As[64][65];
  __shared__ float Bs[64][65];
  const int tid = threadIdx.x;
  const int t0 = blockIdx.y * 64;
  const int n0 = blockIdx.x * 64;
  const int tx = tid & 15, ty = tid >> 4;

  float acc[4][4];
  #pragma unroll
  for (int r = 0; r < 4; ++r)
    #pragma unroll
    for (int c = 0; c < 4; ++c) acc[r][c] = 0.f;

  for (int k0 = 0; k0 < N_IN; k0 += 64) {
    __syncthreads();
    #pragma unroll
    for (int i = 0; i < 4; ++i) {
      int idx = tid + i * 256;
      int row = idx >> 4;
      int k4  = (idx & 15) << 2;
      float4 a = *(const float4*)(in  + (size_t)(t0 + row) * N_IN + k0 + k4);
      As[row][k4+0] = a.x; As[row][k4+1] = a.y; As[row][k4+2] = a.z; As[row][k4+3] = a.w;
      float4 b = *(const float4*)(win + (size_t)(n0 + row) * N_IN + k0 + k4);
      Bs[row][k4+0] = b.x; Bs[row][k4+1] = b.y; Bs[row][k4+2] = b.z; Bs[row][k4+3] = b.w;
    }
    __syncthreads();
    for (int k = 0; k < 64; ++k) {
      float a[4], b[4];
      #pragma unroll
      for (int r = 0; r < 4; ++r) a[r] = As[ty*4+r][k];
      #pragma unroll
      for (int c = 0; c < 4; ++c) b[c] = Bs[tx*4+c][k];
      #pragma unroll
      for (int r = 0; r < 4; ++r)
        #pragma unroll
        for (int c = 0; c < 4; ++c) acc[r][c] += a[r] * b[c];
    }
  }
  #pragma unroll
  for (int r = 0; r < 4; ++r) {
    float4 v = make_float4(acc[r][0], acc[r][1], acc[r][2], acc[r][3]);
    *(float4*)(out + (size_t)(t0 + ty*4 + r) * N_RES + n0 + tx*4) = v;
  }
}

// ---------------- Kernel 2: persistent recurrence --------------------------
// 128 blocks x 256 threads. Block b owns rows [16b,16b+16). Thread t owns
// columns {t + 256*j : j=0..7} (interleaved -> per-step x loads are fully
// coalesced agent-scope dword loads). W block (16x8 per thread) in VGPRs.
// Barrier: per-block monotonic flag (distinct addresses -> parallel stores,
// no RMW serialization); wave 0 polls all 128 flags in one shot via ballot.
__global__ __launch_bounds__(256, 1) void esn_recur(
    const float* __restrict__ wres, float* out, int* ws)
{
  const int b = blockIdx.x;
  const int tid = threadIdx.x;
  const int lane = tid & 63;
  const int wave = tid >> 6;
  const int row0 = b * ROWS;
  const float inv = 0.022097086912079608f;   // 1/sqrt(2048)

  // W block: w[r][j] = W[row0+r][tid + 256*j]; loads coalesced across tid.
  float w[ROWS][8];
  #pragma unroll
  for (int r = 0; r < ROWS; ++r) {
    const float* p = wres + (size_t)(row0 + r) * N_RES + tid;
    #pragma unroll
    for (int j = 0; j < 8; ++j) w[r][j] = p[j * 256];
  }

  __shared__ float red[ROWS][4];
  int* flags = ws;

  // t = 0: x0 = erf(U[0]) * inv  (own columns only; agent-coherent store)
  if (tid < ROWS) {
    float u = out[row0 + tid];
    __hip_atomic_store(out + row0 + tid, erff(u) * inv,
                       __ATOMIC_RELAXED, __HIP_MEMORY_SCOPE_AGENT);
  }
  if (wave == 0) {
    asm volatile("s_waitcnt vmcnt(0)" ::: "memory");   // x0 stores at LLC
    if (lane == 0)
      __hip_atomic_store(flags + b * FSTR, 1, __ATOMIC_RELAXED, __HIP_MEMORY_SCOPE_AGENT);
  }

  for (int t = 1; t < T_SEQ; ++t) {
    // ---- wait: all blocks have completed step t-1 (parallel flag poll)
    if (wave == 0) {
      const int* f0 = flags + lane * FSTR;
      const int* f1 = flags + (lane + 64) * FSTR;
      bool ok;
      do {
        int a = __hip_atomic_load(f0, __ATOMIC_RELAXED, __HIP_MEMORY_SCOPE_AGENT);
        int c = __hip_atomic_load(f1, __ATOMIC_RELAXED, __HIP_MEMORY_SCOPE_AGENT);
        ok = (a >= t) && (c >= t);
      } while (!__all(ok));
    }
    __syncthreads();

    // ---- own U[t] slots (only ever written by this block, later)
    float u = 0.f;
    if (tid < ROWS) u = out[(size_t)t * N_RES + row0 + tid];

    // ---- load x_{t-1}: 8 fully-coalesced agent-scope dword loads
    const float* xrow = out + (size_t)(t - 1) * N_RES + tid;
    float x[8];
    #pragma unroll
    for (int j = 0; j < 8; ++j)
      x[j] = __hip_atomic_load(xrow + j * 256, __ATOMIC_RELAXED, __HIP_MEMORY_SCOPE_AGENT);

    // ---- partial matvec: 16 rows x 8 interleaved cols
    float acc[ROWS];
    #pragma unroll
    for (int r = 0; r < ROWS; ++r) {
      acc[r] = w[r][0]*x[0] + w[r][1]*x[1] + w[r][2]*x[2] + w[r][3]*x[3]
             + w[r][4]*x[4] + w[r][5]*x[5] + w[r][6]*x[6] + w[r][7]*x[7];
    }
    // ---- 64-lane butterfly for all 16 rows
    #pragma unroll
    for (int m = 1; m < 64; m <<= 1) {
      #pragma unroll
      for (int r = 0; r < ROWS; ++r)
        acc[r] += __shfl_xor(acc[r], m, 64);
    }
    if (lane == 0) {
      #pragma unroll
      for (int r = 0; r < ROWS; ++r) red[r][wave] = acc[r];
    }
    __syncthreads();
    if (tid < ROWS) {
      float s = red[tid][0] + red[tid][1] + red[tid][2] + red[tid][3];
      __hip_atomic_store(out + (size_t)t * N_RES + row0 + tid, erff(u + s) * inv,
                         __ATOMIC_RELAXED, __HIP_MEMORY_SCOPE_AGENT);
    }
    // ---- arrive: x_t stores (wave 0) complete at LLC, then raise flag
    if (wave == 0) {
      asm volatile("s_waitcnt vmcnt(0)" ::: "memory");
      if (lane == 0)
        __hip_atomic_store(flags + b * FSTR, t + 1,
                           __ATOMIC_RELAXED, __HIP_MEMORY_SCOPE_AGENT);
    }
  }
}

extern "C" void kernel_launch(void* const* d_in, const int* in_sizes, int n_in,
                              void* d_out, int out_size, void* d_ws, size_t ws_size,
                              hipStream_t stream)
{
  const float* input = (const float*)d_in[0];
  const float* w_in  = (const float*)d_in[1];
  const float* w_res = (const float*)d_in[2];
  float* out = (float*)d_out;
  int* ws = (int*)d_ws;

  size_t clr = ws_size < 4096 ? ws_size : 4096;   // flags occupy 128*16 B = 2 KB
  hipMemsetAsync(d_ws, 0, clr, stream);

  dim3 g1(N_RES / 64, T_SEQ / 64), b1(256);
  hipLaunchKernelGGL(u_gemm, g1, b1, 0, stream, input, w_in, out);

  void* args[] = { (void*)&w_res, (void*)&out, (void*)&ws };
  hipLaunchCooperativeKernel((void*)esn_recur, dim3(NB), dim3(256),
                             args, 0, stream);
}

// Round 4
// 3894.815 us; speedup vs baseline: 5.0526x; 2.0850x over previous
//
#include <hip/hip_runtime.h>
#include <math.h>

#define N_RES 2048
#define N_IN  128
#define T_SEQ 2048
#define NB    128      // blocks in recurrence kernel
#define ROWS  16       // output rows per block (NB*ROWS == N_RES)
#define FSTR  4        // ints per flag slot (fallback path)
#define SENT  0x7F7F7F7Fu   // sentinel bits (3.39e38); |x| <= 0.0222 -> unambiguous

// ---------------- Kernel 1: U = input @ W_in^T  -> d_out (row t = U[t]) ----
__global__ __launch_bounds__(256) void u_gemm(
    const float* __restrict__ in, const float* __restrict__ win,
    float* __restrict__ out)
{
  __shared__ float As[64][65];
  __shared__ float Bs[64][65];
  const int tid = threadIdx.x;
  const int t0 = blockIdx.y * 64;
  const int n0 = blockIdx.x * 64;
  const int tx = tid & 15, ty = tid >> 4;

  float acc[4][4];
  #pragma unroll
  for (int r = 0; r < 4; ++r)
    #pragma unroll
    for (int c = 0; c < 4; ++c) acc[r][c] = 0.f;

  for (int k0 = 0; k0 < N_IN; k0 += 64) {
    __syncthreads();
    #pragma unroll
    for (int i = 0; i < 4; ++i) {
      int idx = tid + i * 256;
      int row = idx >> 4;
      int k4  = (idx & 15) << 2;
      float4 a = *(const float4*)(in  + (size_t)(t0 + row) * N_IN + k0 + k4);
      As[row][k4+0] = a.x; As[row][k4+1] = a.y; As[row][k4+2] = a.z; As[row][k4+3] = a.w;
      float4 b = *(const float4*)(win + (size_t)(n0 + row) * N_IN + k0 + k4);
      Bs[row][k4+0] = b.x; Bs[row][k4+1] = b.y; Bs[row][k4+2] = b.z; Bs[row][k4+3] = b.w;
    }
    __syncthreads();
    for (int k = 0; k < 64; ++k) {
      float a[4], b[4];
      #pragma unroll
      for (int r = 0; r < 4; ++r) a[r] = As[ty*4+r][k];
      #pragma unroll
      for (int c = 0; c < 4; ++c) b[c] = Bs[tx*4+c][k];
      #pragma unroll
      for (int r = 0; r < 4; ++r)
        #pragma unroll
        for (int c = 0; c < 4; ++c) acc[r][c] += a[r] * b[c];
    }
  }
  #pragma unroll
  for (int r = 0; r < 4; ++r) {
    float4 v = make_float4(acc[r][0], acc[r][1], acc[r][2], acc[r][3]);
    *(float4*)(out + (size_t)(t0 + ty*4 + r) * N_RES + n0 + tx*4) = v;
  }
}

// ---- fold-and-keep wave reduction: 16 partials -> 1 full row sum per lane.
// After all levels, lane L holds the complete (64-lane) sum of row
// R(L) = (L&1)*8 + ((L>>1)&1)*4 + ((L>>2)&1)*2 + ((L>>3)&1)  (dup x4).
// 17 shuffles vs 96 for the plain butterfly.
__device__ __forceinline__ float fold_reduce16(float v[16], int lane)
{
  #pragma unroll
  for (int r = 0; r < 8; ++r) {
    float send = (lane & 1) ? v[r] : v[r + 8];
    float recv = __shfl_xor(send, 1, 64);
    v[r] = ((lane & 1) ? v[r + 8] : v[r]) + recv;
  }
  #pragma unroll
  for (int r = 0; r < 4; ++r) {
    float send = (lane & 2) ? v[r] : v[r + 4];
    float recv = __shfl_xor(send, 2, 64);
    v[r] = ((lane & 2) ? v[r + 4] : v[r]) + recv;
  }
  #pragma unroll
  for (int r = 0; r < 2; ++r) {
    float send = (lane & 4) ? v[r] : v[r + 2];
    float recv = __shfl_xor(send, 4, 64);
    v[r] = ((lane & 4) ? v[r + 2] : v[r]) + recv;
  }
  {
    float send = (lane & 8) ? v[0] : v[1];
    float recv = __shfl_xor(send, 8, 64);
    v[0] = ((lane & 8) ? v[1] : v[0]) + recv;
  }
  v[0] += __shfl_xor(v[0], 16, 64);
  v[0] += __shfl_xor(v[0], 32, 64);
  return v[0];
}

// ---------------- Kernel 2a: recurrence, data-as-flag (needs 16MB ws) ------
// x history lives in ws (sentinel-initialized). Producers store x values
// agent-scope; consumers poll the data words themselves until != sentinel.
// One LLC hop per step instead of three. d_out written with plain stores.
__global__ __launch_bounds__(256, 1) void esn_recur_data(
    const float* __restrict__ wres, float* __restrict__ out,
    unsigned int* __restrict__ xbuf)
{
  const int b = blockIdx.x;
  const int tid = threadIdx.x;
  const int lane = tid & 63;
  const int wave = tid >> 6;
  const int row0 = b * ROWS;
  const float inv = 0.022097086912079608f;   // 1/sqrt(2048)
  const int rml = (lane & 1) * 8 + ((lane >> 1) & 1) * 4
                + ((lane >> 2) & 1) * 2 + ((lane >> 3) & 1);

  // W block: w[r][j] = W[row0+r][tid + 256*j]
  float w[ROWS][8];
  #pragma unroll
  for (int r = 0; r < ROWS; ++r) {
    const float* p = wres + (size_t)(row0 + r) * N_RES + tid;
    #pragma unroll
    for (int j = 0; j < 8; ++j) w[r][j] = p[j * 256];
  }

  __shared__ float red[ROWS][4];

  // t = 0
  if (tid < ROWS) {
    float x0 = erff(out[row0 + tid]) * inv;
    out[row0 + tid] = x0;
    __hip_atomic_store(xbuf + row0 + tid, __float_as_uint(x0),
                       __ATOMIC_RELAXED, __HIP_MEMORY_SCOPE_AGENT);
  }

  for (int t = 1; t < T_SEQ; ++t) {
    // own U[t] slots: issue before the poll so latency hides under the spin
    float u = 0.f;
    if (tid < ROWS) u = out[(size_t)t * N_RES + row0 + tid];

    // poll own 8 x words of row t-1 until none is the sentinel
    const unsigned int* xr = xbuf + (size_t)(t - 1) * N_RES + tid;
    unsigned int xb[8];
    bool ready;
    do {
      #pragma unroll
      for (int j = 0; j < 8; ++j)
        xb[j] = __hip_atomic_load(xr + j * 256, __ATOMIC_RELAXED,
                                  __HIP_MEMORY_SCOPE_AGENT);
      ready = true;
      #pragma unroll
      for (int j = 0; j < 8; ++j) ready &= (xb[j] != SENT);
    } while (!ready);

    float x[8];
    #pragma unroll
    for (int j = 0; j < 8; ++j) x[j] = __uint_as_float(xb[j]);

    float acc[ROWS];
    #pragma unroll
    for (int r = 0; r < ROWS; ++r) {
      acc[r] = w[r][0]*x[0] + w[r][1]*x[1] + w[r][2]*x[2] + w[r][3]*x[3]
             + w[r][4]*x[4] + w[r][5]*x[5] + w[r][6]*x[6] + w[r][7]*x[7];
    }
    float s = fold_reduce16(acc, lane);
    if (lane < ROWS) red[rml][wave] = s;
    __syncthreads();
    if (tid < ROWS) {
      float tot = red[tid][0] + red[tid][1] + red[tid][2] + red[tid][3];
      float xt = erff(u + tot) * inv;
      out[(size_t)t * N_RES + row0 + tid] = xt;                       // plain
      __hip_atomic_store(xbuf + (size_t)t * N_RES + row0 + tid,
                         __float_as_uint(xt),
                         __ATOMIC_RELAXED, __HIP_MEMORY_SCOPE_AGENT); // signal
    }
    __syncthreads();   // red[] reuse guard
  }
}

// ---------------- Kernel 2b: fallback (flag barrier, R2 scheme) ------------
__global__ __launch_bounds__(256, 1) void esn_recur_flags(
    const float* __restrict__ wres, float* out, int* ws)
{
  const int b = blockIdx.x;
  const int tid = threadIdx.x;
  const int lane = tid & 63;
  const int wave = tid >> 6;
  const int row0 = b * ROWS;
  const float inv = 0.022097086912079608f;

  float w[ROWS][8];
  #pragma unroll
  for (int r = 0; r < ROWS; ++r) {
    const float* p = wres + (size_t)(row0 + r) * N_RES + tid;
    #pragma unroll
    for (int j = 0; j < 8; ++j) w[r][j] = p[j * 256];
  }

  __shared__ float red[ROWS][4];
  int* flags = ws;

  if (tid < ROWS) {
    float u = out[row0 + tid];
    __hip_atomic_store(out + row0 + tid, erff(u) * inv,
                       __ATOMIC_RELAXED, __HIP_MEMORY_SCOPE_AGENT);
  }
  if (wave == 0) {
    asm volatile("s_waitcnt vmcnt(0)" ::: "memory");
    if (lane == 0)
      __hip_atomic_store(flags + b * FSTR, 1, __ATOMIC_RELAXED, __HIP_MEMORY_SCOPE_AGENT);
  }

  for (int t = 1; t < T_SEQ; ++t) {
    if (wave == 0) {
      const int* f0 = flags + lane * FSTR;
      const int* f1 = flags + (lane + 64) * FSTR;
      bool ok;
      do {
        int a = __hip_atomic_load(f0, __ATOMIC_RELAXED, __HIP_MEMORY_SCOPE_AGENT);
        int c = __hip_atomic_load(f1, __ATOMIC_RELAXED, __HIP_MEMORY_SCOPE_AGENT);
        ok = (a >= t) && (c >= t);
      } while (!__all(ok));
    }
    __syncthreads();

    float u = 0.f;
    if (tid < ROWS) u = out[(size_t)t * N_RES + row0 + tid];

    const float* xrow = out + (size_t)(t - 1) * N_RES + tid;
    float x[8];
    #pragma unroll
    for (int j = 0; j < 8; ++j)
      x[j] = __hip_atomic_load(xrow + j * 256, __ATOMIC_RELAXED, __HIP_MEMORY_SCOPE_AGENT);

    float acc[ROWS];
    #pragma unroll
    for (int r = 0; r < ROWS; ++r) {
      acc[r] = w[r][0]*x[0] + w[r][1]*x[1] + w[r][2]*x[2] + w[r][3]*x[3]
             + w[r][4]*x[4] + w[r][5]*x[5] + w[r][6]*x[6] + w[r][7]*x[7];
    }
    #pragma unroll
    for (int m = 1; m < 64; m <<= 1) {
      #pragma unroll
      for (int r = 0; r < ROWS; ++r)
        acc[r] += __shfl_xor(acc[r], m, 64);
    }
    if (lane == 0) {
      #pragma unroll
      for (int r = 0; r < ROWS; ++r) red[r][wave] = acc[r];
    }
    __syncthreads();
    if (tid < ROWS) {
      float s = red[tid][0] + red[tid][1] + red[tid][2] + red[tid][3];
      __hip_atomic_store(out + (size_t)t * N_RES + row0 + tid, erff(u + s) * inv,
                         __ATOMIC_RELAXED, __HIP_MEMORY_SCOPE_AGENT);
    }
    if (wave == 0) {
      asm volatile("s_waitcnt vmcnt(0)" ::: "memory");
      if (lane == 0)
        __hip_atomic_store(flags + b * FSTR, t + 1,
                           __ATOMIC_RELAXED, __HIP_MEMORY_SCOPE_AGENT);
    }
  }
}

extern "C" void kernel_launch(void* const* d_in, const int* in_sizes, int n_in,
                              void* d_out, int out_size, void* d_ws, size_t ws_size,
                              hipStream_t stream)
{
  const float* input = (const float*)d_in[0];
  const float* w_in  = (const float*)d_in[1];
  const float* w_res = (const float*)d_in[2];
  float* out = (float*)d_out;

  const size_t xbytes = (size_t)T_SEQ * N_RES * sizeof(float);  // 16 MiB

  dim3 g1(N_RES / 64, T_SEQ / 64), b1(256);
  hipLaunchKernelGGL(u_gemm, g1, b1, 0, stream, input, w_in, out);

  if (ws_size >= xbytes) {
    unsigned int* xbuf = (unsigned int*)d_ws;
    hipMemsetAsync(d_ws, 0x7F, xbytes, stream);   // sentinel-fill x history
    void* args[] = { (void*)&w_res, (void*)&out, (void*)&xbuf };
    hipLaunchCooperativeKernel((void*)esn_recur_data, dim3(NB), dim3(256),
                               args, 0, stream);
  } else {
    int* ws = (int*)d_ws;
    size_t clr = ws_size < 4096 ? ws_size : 4096;
    hipMemsetAsync(d_ws, 0, clr, stream);
    void* args[] = { (void*)&w_res, (void*)&out, (void*)&ws };
    hipLaunchCooperativeKernel((void*)esn_recur_flags, dim3(NB), dim3(256),
                               args, 0, stream);
  }
}